// Round 7
// baseline (664.701 us; speedup 1.0000x reference)
//
#include <hip/hip_runtime.h>

// ---------------- constants (reference is compile-time fixed) ----------------
#define T_TOK 2048
#define DM    4096
#define NH    32
#define KVH   8
#define HD    128
#define QKV_N 6144          // 4096 q + 1024 k + 1024 v
#define KOFF  4096
#define VOFF  5120
#define SCALE 0.08838834764831845f   // 128^-0.5

typedef __attribute__((ext_vector_type(8))) short  short8;   // 8 bf16 (4 VGPRs)
typedef __attribute__((ext_vector_type(4))) float  floatx4;  // MFMA acc

__device__ __forceinline__ ushort f2bf(float f) {
  union { float f; unsigned u; } x; x.f = f;
  unsigned u = x.u;
  return (ushort)((u + 0x7fffu + ((u >> 16) & 1u)) >> 16);   // RNE
}
__device__ __forceinline__ float bf2f(ushort h) {
  union { unsigned u; float f; } x; x.u = ((unsigned)h) << 16;
  return x.f;
}

// ---------------- fp32 -> bf16 cast (vectorized) ----------------
__global__ void __launch_bounds__(256) cast_bf16_kernel(const float* __restrict__ x,
                                                        ushort* __restrict__ y, int n4) {
  int i = blockIdx.x * 256 + threadIdx.x;
  if (i >= n4) return;
  float4 v = ((const float4*)x)[i];
  ushort4 o;
  o.x = f2bf(v.x); o.y = f2bf(v.y); o.z = f2bf(v.z); o.w = f2bf(v.w);
  ((ushort4*)y)[i] = o;
}

// ---------------- fp32 partial add (split-K reduction) ----------------
__global__ void __launch_bounds__(256) add_f32_kernel(const float4* __restrict__ a,
                                                      const float4* __restrict__ b,
                                                      float4* __restrict__ o, int n4) {
  int i = blockIdx.x * 256 + threadIdx.x;
  if (i >= n4) return;
  float4 x = a[i], y = b[i];
  o[i] = make_float4(x.x + y.x, x.y + y.y, x.z + y.z, x.w + y.w);
}

// ---------------- async global->LDS, 16B per lane ----------------
__device__ __forceinline__ void gld_lds16(const ushort* g, ushort* l) {
  __builtin_amdgcn_global_load_lds((const __attribute__((address_space(1))) unsigned int*)g,
                                   (__attribute__((address_space(3))) unsigned int*)l,
                                   16, 0, 0);
}

// ============================================================================
// 256x256 8-phase GEMM — EXACT round-2 structure (best measured: 142 µs QKV,
// MfmaUtil 29, conflicts 0) + round-3's split-K plumbing (passed).
// Runtime LDS buffer index (R3's compile-time unroll was slightly WORSE:
// 148 vs 142 — addressing theory falsified). Same-phase read+consume; reads
// 12/4/8/0 across phases; staging ph1: A1(t+1), ph3: B0(t+2), ph4: B1+A0(t+2);
// vmcnt(6) once per tile at ph4 (never 0 in steady state); bare s_barrier.
// ============================================================================
template <int MLO, int NLO>
__device__ __forceinline__ void mfma_quad(floatx4 (&acc)[8][4],
                                          const short8 (&afr)[4][2],
                                          const short8 (&bfr)[4][2]) {
  __builtin_amdgcn_s_setprio(1);
#pragma unroll
  for (int ks = 0; ks < 2; ++ks)
#pragma unroll
    for (int mi = 0; mi < 4; ++mi)
#pragma unroll
      for (int ni = 0; ni < 2; ++ni)
        acc[MLO + mi][NLO + ni] = __builtin_amdgcn_mfma_f32_16x16x32_bf16(
            afr[mi][ks], bfr[NLO + ni][ks], acc[MLO + mi][NLO + ni], 0, 0, 0);
  __builtin_amdgcn_s_setprio(0);
}

// stage one 128x64 half-tile (16 KiB): 2 x global_load_lds per thread.
// linear LDS dest; source column chunk pre-swizzled by (row&7)  (rule 21).
__device__ __forceinline__ void stage_half(const ushort* __restrict__ G, size_t row0,
                                           int K, int k0, ushort* lbase, int tid) {
#pragma unroll
  for (int j = 0; j < 2; ++j) {
    int row   = j * 64 + (tid >> 3);
    int chunk = (tid & 7) ^ (row & 7);
    gld_lds16(G + (row0 + (size_t)row) * K + k0 + chunk * 8,
              lbase + (size_t)(j * 512 + tid) * 8);
  }
}

__global__ void __launch_bounds__(512, 2)
gemm256(const ushort* __restrict__ A, const ushort* __restrict__ B,
        ushort* __restrict__ Cb, float* __restrict__ Cf,
        int N, int K, int Kloc, int KS, int mode) {
  __shared__ __align__(16) ushort As[2][2][128][64];   // 64 KiB
  __shared__ __align__(16) ushort Bs[2][2][128][64];   // 64 KiB

  const int tid = threadIdx.x;
  const int lane = tid & 63, wv = tid >> 6;
  const int r = lane & 15, g = lane >> 4;
  const int wm = wv >> 2, wn = wv & 3;              // 2M x 4N wave grid

  // XCD-aware swizzle (nwg % 8 == 0 for all launches: 192, 256)
  const int nwg = (int)gridDim.x;
  const int wg  = (int)blockIdx.x;
  const int wgs = (wg & 7) * (nwg >> 3) + (wg >> 3);
  const int nbx = N >> 8;
  const int by  = wgs / (nbx * KS);
  const int rem = wgs - by * nbx * KS;
  const int bx  = rem / KS;
  const int ks_ = rem - bx * KS;                    // K-slice id
  const int bm = by * 256, bn = bx * 256;
  const int koff = ks_ * Kloc;

  const int NT = Kloc >> 6;                         // 64-wide K tiles

  floatx4 acc[8][4];
#pragma unroll
  for (int mi = 0; mi < 8; ++mi)
#pragma unroll
    for (int ni = 0; ni < 4; ++ni) acc[mi][ni] = (floatx4){0.f, 0.f, 0.f, 0.f};

  // ---- prologue: tile0 (B0,B1,A0,A1) + tile1 (B0,B1,A0) = 7 half-tiles ----
  stage_half(B, bn,       K, koff, &Bs[0][0][0][0], tid);
  stage_half(B, bn + 128, K, koff, &Bs[0][1][0][0], tid);
  stage_half(A, bm,       K, koff, &As[0][0][0][0], tid);
  stage_half(A, bm + 128, K, koff, &As[0][1][0][0], tid);
  if (NT > 1) {
    stage_half(B, bn,       K, koff + 64, &Bs[1][0][0][0], tid);
    stage_half(B, bn + 128, K, koff + 64, &Bs[1][1][0][0], tid);
    stage_half(A, bm,       K, koff + 64, &As[1][0][0][0], tid);
    asm volatile("s_waitcnt vmcnt(6)");   // tile0's 8 loads landed
  } else {
    asm volatile("s_waitcnt vmcnt(0)");
  }
  __builtin_amdgcn_s_barrier();

  short8 afr[4][2], bfr[4][2];
  const int cswz = (r & 15 & 7) << 3;   // == (r&7)<<3, element-index XOR swz

  for (int t = 0; t < NT; ++t) {
    const int buf = t & 1;
    const ushort* Ab = &As[buf][wm][0][0];
    const ushort* Bb = &Bs[buf][wn >> 1][0][0];
    const int brow = (wn & 1) * 64;

    // -------- phase 1: read bfr[0..1] + afr[0..3] (12 reads); stage A1(t+1)
#pragma unroll
    for (int ni = 0; ni < 2; ++ni)
#pragma unroll
      for (int ks = 0; ks < 2; ++ks)
        bfr[ni][ks] = *(const short8*)&Bb[(brow + ni * 16 + r) * 64 +
                                          ((ks * 32 + g * 8) ^ cswz)];
#pragma unroll
    for (int m = 0; m < 4; ++m)
#pragma unroll
      for (int ks = 0; ks < 2; ++ks)
        afr[m][ks] = *(const short8*)&Ab[(m * 16 + r) * 64 +
                                         ((ks * 32 + g * 8) ^ cswz)];
    if (t + 1 < NT) stage_half(A, bm + 128, K, koff + (t + 1) * 64,
                               &As[(t + 1) & 1][1][0][0], tid);
    __builtin_amdgcn_s_barrier();
    mfma_quad<0, 0>(acc, afr, bfr);
    __builtin_amdgcn_s_barrier();

    // -------- phase 2: read bfr[2..3] (4 reads)
#pragma unroll
    for (int ni = 2; ni < 4; ++ni)
#pragma unroll
      for (int ks = 0; ks < 2; ++ks)
        bfr[ni][ks] = *(const short8*)&Bb[(brow + ni * 16 + r) * 64 +
                                          ((ks * 32 + g * 8) ^ cswz)];
    __builtin_amdgcn_s_barrier();
    mfma_quad<0, 2>(acc, afr, bfr);
    __builtin_amdgcn_s_barrier();

    // -------- phase 3: re-read afr = A rows 64..127 (8 reads); stage B0(t+2)
#pragma unroll
    for (int m = 0; m < 4; ++m)
#pragma unroll
      for (int ks = 0; ks < 2; ++ks)
        afr[m][ks] = *(const short8*)&Ab[((64 + m * 16) + r) * 64 +
                                         ((ks * 32 + g * 8) ^ cswz)];
    if (t + 2 < NT) stage_half(B, bn, K, koff + (t + 2) * 64, &Bs[buf][0][0][0], tid);
    __builtin_amdgcn_s_barrier();
    mfma_quad<4, 2>(acc, afr, bfr);
    __builtin_amdgcn_s_barrier();

    // -------- phase 4: stage B1(t+2) + A0(t+2); counted vmcnt; last quad
    if (t + 2 < NT) {
      stage_half(B, bn + 128, K, koff + (t + 2) * 64, &Bs[buf][1][0][0], tid);
      stage_half(A, bm,       K, koff + (t + 2) * 64, &As[buf][0][0][0], tid);
    }
    if (t < NT - 2) asm volatile("s_waitcnt vmcnt(6)");  // tile t+1 landed
    else            asm volatile("s_waitcnt vmcnt(0)");  // epilogue drain
    __builtin_amdgcn_s_barrier();
    mfma_quad<4, 0>(acc, afr, bfr);
    __builtin_amdgcn_s_barrier();
  }

  // ---- epilogue: C/D layout col=lane&15, row=(lane>>4)*4+reg --------------
  float* Cfo = Cf + (size_t)ks_ * ((size_t)2048 * N);   // split-K partial slab
#pragma unroll
  for (int mi = 0; mi < 8; ++mi)
#pragma unroll
    for (int v = 0; v < 4; ++v) {
      int row = bm + wm * 128 + mi * 16 + g * 4 + v;
#pragma unroll
      for (int ni = 0; ni < 4; ++ni) {
        int col = bn + wn * 64 + ni * 16 + r;
        float x = acc[mi][ni][v];
        if (mode == 0) {
          x = fminf(8.0f, fmaxf(-8.0f, x));
          Cb[(size_t)row * N + col] = f2bf(x);
        } else {
          Cfo[(size_t)row * N + col] = x;
        }
      }
    }
}

// ---------------- RoPE (NeoX half-split) on q and k, q pre-scaled ----------------
// grid (10, 2048), block 256: h = bx*4 + tid/64 in [0,40), d = tid&63
__global__ void __launch_bounds__(256) rope_kernel(ushort* __restrict__ qkv,
                                                   const float* __restrict__ cosb,
                                                   const float* __restrict__ sinb) {
  int t = blockIdx.y;
  int h = blockIdx.x * 4 + (threadIdx.x >> 6);
  int d = threadIdx.x & 63;
  size_t base = (size_t)t * QKV_N + (h < NH ? h * HD : KOFF + (h - NH) * HD);
  float x1 = bf2f(qkv[base + d]);
  float x2 = bf2f(qkv[base + 64 + d]);
  float c = cosb[t * 64 + d], s = sinb[t * 64 + d];
  float y1 = x1 * c - x2 * s;
  float y2 = x2 * c + x1 * s;
  if (h < NH) { y1 *= SCALE; y2 *= SCALE; }
  qkv[base + d]      = f2bf(y1);
  qkv[base + 64 + d] = f2bf(y2);
}

// ---------------- V transpose: vt[kv][d][t] = v[t][kv][d] ----------------
__global__ void __launch_bounds__(256) vtrans_kernel(const ushort* __restrict__ qkv,
                                                     ushort* __restrict__ vt) {
  int idx = blockIdx.x * 256 + threadIdx.x;   // kv(3b) | d(7b) | t(11b)
  int t  = idx & (T_TOK - 1);
  int d  = (idx >> 11) & (HD - 1);
  int kv = idx >> 18;
  vt[idx] = qkv[(size_t)t * QKV_N + VOFF + kv * HD + d];
}

// ---------------- flash attention: block = (q-tile 64, head), 4 waves x 16 rows --
// K/V per kv-head = 0.5 MB -> fully L2-resident. Guide common-mistake #7
// (measured +26% on attn): LDS-staging L2-fit data is pure overhead. This
// version reads K and V^T fragments DIRECTLY global->VGPR at the exact
// addresses the old staging produced (math unchanged), deleting Ks/Vts and
// ALL barriers in the loop. Ps (P bf16 round-trip) stays: wave-private,
// in-wave lgkm ordering (proven in rounds 4/6). T5 setprio around MFMA
// bursts (+4-7% measured on attn).
__global__ void __launch_bounds__(256) attn_kernel(const ushort* __restrict__ qkv,
                                                   const ushort* __restrict__ vt,
                                                   ushort* __restrict__ o) {
  __shared__ ushort Ps[4][16][72];  // per-wave P round-trip (C->A layout)

  const int tid = threadIdx.x, wave = tid >> 6, lane = tid & 63;
  const int r = lane & 15, g = lane >> 4;
  const int qtile = blockIdx.x, head = blockIdx.y, kvh = head >> 2;
  const int q0 = qtile * 64;
  int s0;                                            // segment start (hardcoded cu)
  if (q0 < 512) s0 = 0; else if (q0 < 1280) s0 = 512;
  else if (q0 < 1664) s0 = 1280; else s0 = 1664;

  // Q fragments straight from global (A-layout: m=lane&15, k=(lane>>4)*8+j)
  short8 qf[4];
  const int qrow = q0 + wave * 16 + r;
#pragma unroll
  for (int ks = 0; ks < 4; ks++)
    qf[ks] = *(const short8*)&qkv[(size_t)qrow * QKV_N + head * HD + ks * 32 + g * 8];

  floatx4 zero = {0.f, 0.f, 0.f, 0.f};
  floatx4 oacc[8];
#pragma unroll
  for (int b = 0; b < 8; b++) oacc[b] = zero;
  float mrun[4] = {-1e30f, -1e30f, -1e30f, -1e30f};
  float lrun[4] = {0.f, 0.f, 0.f, 0.f};

  const size_t kcol  = (size_t)KOFF + kvh * HD;
  const size_t vbase = (size_t)kvh * HD * T_TOK;

  for (int k0 = s0; k0 < q0 + 64; k0 += 64) {
    // ---- S = Q K^T, K fragments direct from global (L2-hit) ----
    floatx4 sacc[4];
#pragma unroll
    for (int s = 0; s < 4; s++) sacc[s] = zero;
#pragma unroll
    for (int s = 0; s < 4; s++) {
      short8 kf[4];
#pragma unroll
      for (int ks = 0; ks < 4; ks++)
        kf[ks] = *(const short8*)&qkv[(size_t)(k0 + s * 16 + r) * QKV_N +
                                      kcol + ks * 32 + g * 8];
      __builtin_amdgcn_s_setprio(1);
#pragma unroll
      for (int ks = 0; ks < 4; ks++)
        sacc[s] = __builtin_amdgcn_mfma_f32_16x16x32_bf16(qf[ks], kf[ks], sacc[s], 0, 0, 0);
      __builtin_amdgcn_s_setprio(0);
    }

    // ---- causal mask (only diagonal tile needs it) ----
    const bool diag = (k0 == q0);
    float sv[4][4];
#pragma unroll
    for (int s = 0; s < 4; s++)
#pragma unroll
      for (int v = 0; v < 4; v++) {
        float x = sacc[s][v];
        if (diag) {
          int ka = k0 + s * 16 + r;            // key abs (col = lane&15)
          int qa = q0 + wave * 16 + g * 4 + v; // q   abs (row = (lane>>4)*4+reg)
          if (ka > qa) x = -1e30f;
        }
        sv[s][v] = x;
      }

    // ---- online softmax (rows live across lane&15 within each 16-lane group) --
    float rmax[4];
#pragma unroll
    for (int v = 0; v < 4; v++)
      rmax[v] = fmaxf(fmaxf(sv[0][v], sv[1][v]), fmaxf(sv[2][v], sv[3][v]));
#pragma unroll
    for (int off = 1; off < 16; off <<= 1)
#pragma unroll
      for (int v = 0; v < 4; v++)
        rmax[v] = fmaxf(rmax[v], __shfl_xor(rmax[v], off, 64));

    float newm[4], alpha[4];
#pragma unroll
    for (int v = 0; v < 4; v++) {
      newm[v]  = fmaxf(mrun[v], rmax[v]);
      alpha[v] = __expf(mrun[v] - newm[v]);
      mrun[v]  = newm[v];
    }

    float pv[4][4];
    float rsum[4] = {0.f, 0.f, 0.f, 0.f};
#pragma unroll
    for (int s = 0; s < 4; s++)
#pragma unroll
      for (int v = 0; v < 4; v++) {
        float p = __expf(sv[s][v] - newm[v]);
        pv[s][v] = p;
        rsum[v] += p;
      }
#pragma unroll
    for (int off = 1; off < 16; off <<= 1)
#pragma unroll
      for (int v = 0; v < 4; v++)
        rsum[v] += __shfl_xor(rsum[v], off, 64);
#pragma unroll
    for (int v = 0; v < 4; v++) lrun[v] = lrun[v] * alpha[v] + rsum[v];
#pragma unroll
    for (int b = 0; b < 8; b++)
#pragma unroll
      for (int v = 0; v < 4; v++) oacc[b][v] *= alpha[v];

    // ---- P: C-layout -> A-layout via per-wave LDS round trip (wave-private,
    //      in-wave lgkm ordering suffices, no barrier) ----
#pragma unroll
    for (int s = 0; s < 4; s++)
#pragma unroll
      for (int v = 0; v < 4; v++)
        Ps[wave][g * 4 + v][s * 16 + r] = f2bf(pv[s][v]);

    short8 pf0 = *(const short8*)&Ps[wave][r][g * 8];
    short8 pf1 = *(const short8*)&Ps[wave][r][32 + g * 8];

    // ---- O += P V : V^T fragments direct from global (L2-hit) ----
#pragma unroll
    for (int b = 0; b < 8; b++) {
      short8 v0 = *(const short8*)&vt[vbase + (size_t)(b * 16 + r) * T_TOK + k0 + g * 8];
      short8 v1 = *(const short8*)&vt[vbase + (size_t)(b * 16 + r) * T_TOK + k0 + 32 + g * 8];
      __builtin_amdgcn_s_setprio(1);
      oacc[b] = __builtin_amdgcn_mfma_f32_16x16x32_bf16(pf0, v0, oacc[b], 0, 0, 0);
      oacc[b] = __builtin_amdgcn_mfma_f32_16x16x32_bf16(pf1, v1, oacc[b], 0, 0, 0);
      __builtin_amdgcn_s_setprio(0);
    }
  }

  // ---- epilogue: O /= l, write bf16 ----
  float rinv[4];
#pragma unroll
  for (int v = 0; v < 4; v++) rinv[v] = 1.0f / lrun[v];
#pragma unroll
  for (int b = 0; b < 8; b++)
#pragma unroll
    for (int v = 0; v < 4; v++) {
      int qa = q0 + wave * 16 + g * 4 + v;
      o[(size_t)qa * DM + head * HD + b * 16 + r] = f2bf(oacc[b][v] * rinv[v]);
    }
}

// ---------------- launch ----------------
extern "C" void kernel_launch(void* const* d_in, const int* in_sizes, int n_in,
                              void* d_out, int out_size, void* d_ws, size_t ws_size,
                              hipStream_t stream) {
  const float* hs   = (const float*)d_in[0];   // 2048 x 4096
  const float* wqkv = (const float*)d_in[1];   // 6144 x 4096
  const float* wo   = (const float*)d_in[2];   // 4096 x 4096
  const float* cosb = (const float*)d_in[3];   // 2048 x 64
  const float* sinb = (const float*)d_in[4];   // 2048 x 64
  float* out = (float*)d_out;                  // 2048 x 4096 fp32

  char* w = (char*)d_ws;
  ushort* h_bf   = (ushort*)(w);                  // 16,777,216 B
  ushort* wq_bf  = (ushort*)(w + 16777216);       // 50,331,648 B
  ushort* wo_bf  = (ushort*)(w + 67108864);       // 33,554,432 B
  ushort* qkv_bf = (ushort*)(w + 100663296);      // 25,165,824 B
  ushort* vt     = (ushort*)(w + 125829120);      //  4,194,304 B
  ushort* ao_bf  = (ushort*)(w + 130023424);      // 16,777,216 B  (total ~147 MB)
  // split-K partials reuse [w, w+67.1MB) — h_bf/wq_bf are dead after QKV GEMM
  float*  part   = (float*)(w);                   // 2 x 2048x4096 fp32 = 67,108,864 B

  cast_bf16_kernel<<<8192,  256, 0, stream>>>(hs,   h_bf,  2097152);
  cast_bf16_kernel<<<24576, 256, 0, stream>>>(wqkv, wq_bf, 6291456);
  cast_bf16_kernel<<<16384, 256, 0, stream>>>(wo,   wo_bf, 4194304);

  // QKV: M=2048, N=6144, K=4096 -> 24*8 = 192 blocks, no split
  gemm256<<<dim3(192), 512, 0, stream>>>(h_bf, wq_bf, qkv_bf, nullptr,
                                         QKV_N, DM, DM, 1, 0);
  rope_kernel<<<dim3(10, T_TOK), 256, 0, stream>>>(qkv_bf, cosb, sinb);
  vtrans_kernel<<<8192, 256, 0, stream>>>(qkv_bf, vt);
  attn_kernel<<<dim3(32, 32), 256, 0, stream>>>(qkv_bf, vt, ao_bf);
  // O-proj: M=2048, N=4096, K=4096, split-K=2 -> 16*8*2 = 256 blocks
  gemm256<<<dim3(256), 512, 0, stream>>>(ao_bf, wo_bf, nullptr, part,
                                         DM, DM, 2048, 2, 1);
  add_f32_kernel<<<8192, 256, 0, stream>>>((const float4*)part,
                                           (const float4*)(part + (size_t)2048 * 4096),
                                           (float4*)out, 2097152);
}

// Round 8
// 540.988 us; speedup vs baseline: 1.2287x; 1.2287x over previous
//
#include <hip/hip_runtime.h>

// ---------------- constants (reference is compile-time fixed) ----------------
#define T_TOK 2048
#define DM    4096
#define NH    32
#define KVH   8
#define HD    128
#define QKV_N 6144          // 4096 q + 1024 k + 1024 v
#define KOFF  4096
#define VOFF  5120
#define SCALE 0.08838834764831845f   // 128^-0.5

typedef __attribute__((ext_vector_type(8))) short  short8;   // 8 bf16 (4 VGPRs)
typedef __attribute__((ext_vector_type(4))) float  floatx4;  // MFMA acc

__device__ __forceinline__ ushort f2bf(float f) {
  union { float f; unsigned u; } x; x.f = f;
  unsigned u = x.u;
  return (ushort)((u + 0x7fffu + ((u >> 16) & 1u)) >> 16);   // RNE
}
__device__ __forceinline__ float bf2f(ushort h) {
  union { unsigned u; float f; } x; x.u = ((unsigned)h) << 16;
  return x.f;
}

// ---------------- fused fp32 -> bf16 cast of all three inputs ----------------
// ranges (in float4 units): hs 2,097,152 | wqkv 6,291,456 | wo 4,194,304.
// boundaries are multiples of 256 -> block-uniform branches. one launch.
__global__ void __launch_bounds__(256) cast3_kernel(const float* __restrict__ hs,
                                                    const float* __restrict__ wqkv,
                                                    const float* __restrict__ wo,
                                                    ushort* __restrict__ h_bf,
                                                    ushort* __restrict__ wq_bf,
                                                    ushort* __restrict__ wo_bf) {
  int i = blockIdx.x * 256 + threadIdx.x;
  const float* src; ushort* dst; int j;
  if (i < 2097152)        { src = hs;   dst = h_bf;  j = i; }
  else if (i < 8388608)   { src = wqkv; dst = wq_bf; j = i - 2097152; }
  else                    { src = wo;   dst = wo_bf; j = i - 8388608; }
  float4 v = ((const float4*)src)[j];
  ushort4 o;
  o.x = f2bf(v.x); o.y = f2bf(v.y); o.z = f2bf(v.z); o.w = f2bf(v.w);
  ((ushort4*)dst)[j] = o;
}

// ---------------- fp32 partial add (split-K reduction) ----------------
__global__ void __launch_bounds__(256) add_f32_kernel(const float4* __restrict__ a,
                                                      const float4* __restrict__ b,
                                                      float4* __restrict__ o, int n4) {
  int i = blockIdx.x * 256 + threadIdx.x;
  if (i >= n4) return;
  float4 x = a[i], y = b[i];
  o[i] = make_float4(x.x + y.x, x.y + y.y, x.z + y.z, x.w + y.w);
}

// ---------------- async global->LDS, 16B per lane ----------------
__device__ __forceinline__ void gld_lds16(const ushort* g, ushort* l) {
  __builtin_amdgcn_global_load_lds((const __attribute__((address_space(1))) unsigned int*)g,
                                   (__attribute__((address_space(3))) unsigned int*)l,
                                   16, 0, 0);
}

// ============================================================================
// 256x256 8-phase GEMM — EXACT round-2 structure (best measured: 142 µs QKV,
// MfmaUtil 29, conflicts 0) + round-3's split-K plumbing (passed).
// Same-phase read+consume; reads 12/4/8/0 across phases; staging ph1: A1(t+1),
// ph3: B0(t+2), ph4: B1+A0(t+2); vmcnt(6) once per tile at ph4 (never 0 in
// steady state); bare s_barrier.
// ============================================================================
template <int MLO, int NLO>
__device__ __forceinline__ void mfma_quad(floatx4 (&acc)[8][4],
                                          const short8 (&afr)[4][2],
                                          const short8 (&bfr)[4][2]) {
  __builtin_amdgcn_s_setprio(1);
#pragma unroll
  for (int ks = 0; ks < 2; ++ks)
#pragma unroll
    for (int mi = 0; mi < 4; ++mi)
#pragma unroll
      for (int ni = 0; ni < 2; ++ni)
        acc[MLO + mi][NLO + ni] = __builtin_amdgcn_mfma_f32_16x16x32_bf16(
            afr[mi][ks], bfr[NLO + ni][ks], acc[MLO + mi][NLO + ni], 0, 0, 0);
  __builtin_amdgcn_s_setprio(0);
}

// stage one 128x64 half-tile (16 KiB): 2 x global_load_lds per thread.
// linear LDS dest; source column chunk pre-swizzled by (row&7)  (rule 21).
__device__ __forceinline__ void stage_half(const ushort* __restrict__ G, size_t row0,
                                           int K, int k0, ushort* lbase, int tid) {
#pragma unroll
  for (int j = 0; j < 2; ++j) {
    int row   = j * 64 + (tid >> 3);
    int chunk = (tid & 7) ^ (row & 7);
    gld_lds16(G + (row0 + (size_t)row) * K + k0 + chunk * 8,
              lbase + (size_t)(j * 512 + tid) * 8);
  }
}

__global__ void __launch_bounds__(512, 2)
gemm256(const ushort* __restrict__ A, const ushort* __restrict__ B,
        ushort* __restrict__ Cb, float* __restrict__ Cf,
        int N, int K, int Kloc, int KS, int mode) {
  __shared__ __align__(16) ushort As[2][2][128][64];   // 64 KiB
  __shared__ __align__(16) ushort Bs[2][2][128][64];   // 64 KiB

  const int tid = threadIdx.x;
  const int lane = tid & 63, wv = tid >> 6;
  const int r = lane & 15, g = lane >> 4;
  const int wm = wv >> 2, wn = wv & 3;              // 2M x 4N wave grid

  // XCD-aware swizzle (nwg % 8 == 0 for all launches: 192, 256)
  const int nwg = (int)gridDim.x;
  const int wg  = (int)blockIdx.x;
  const int wgs = (wg & 7) * (nwg >> 3) + (wg >> 3);
  const int nbx = N >> 8;
  const int by  = wgs / (nbx * KS);
  const int rem = wgs - by * nbx * KS;
  const int bx  = rem / KS;
  const int ks_ = rem - bx * KS;                    // K-slice id
  const int bm = by * 256, bn = bx * 256;
  const int koff = ks_ * Kloc;

  const int NT = Kloc >> 6;                         // 64-wide K tiles

  floatx4 acc[8][4];
#pragma unroll
  for (int mi = 0; mi < 8; ++mi)
#pragma unroll
    for (int ni = 0; ni < 4; ++ni) acc[mi][ni] = (floatx4){0.f, 0.f, 0.f, 0.f};

  // ---- prologue: tile0 (B0,B1,A0,A1) + tile1 (B0,B1,A0) = 7 half-tiles ----
  stage_half(B, bn,       K, koff, &Bs[0][0][0][0], tid);
  stage_half(B, bn + 128, K, koff, &Bs[0][1][0][0], tid);
  stage_half(A, bm,       K, koff, &As[0][0][0][0], tid);
  stage_half(A, bm + 128, K, koff, &As[0][1][0][0], tid);
  if (NT > 1) {
    stage_half(B, bn,       K, koff + 64, &Bs[1][0][0][0], tid);
    stage_half(B, bn + 128, K, koff + 64, &Bs[1][1][0][0], tid);
    stage_half(A, bm,       K, koff + 64, &As[1][0][0][0], tid);
    asm volatile("s_waitcnt vmcnt(6)");   // tile0's 8 loads landed
  } else {
    asm volatile("s_waitcnt vmcnt(0)");
  }
  __builtin_amdgcn_s_barrier();

  short8 afr[4][2], bfr[4][2];
  const int cswz = (r & 7) << 3;        // element-index XOR for 16B-chunk swz

  for (int t = 0; t < NT; ++t) {
    const int buf = t & 1;
    const ushort* Ab = &As[buf][wm][0][0];
    const ushort* Bb = &Bs[buf][wn >> 1][0][0];
    const int brow = (wn & 1) * 64;

    // -------- phase 1: read bfr[0..1] + afr[0..3] (12 reads); stage A1(t+1)
#pragma unroll
    for (int ni = 0; ni < 2; ++ni)
#pragma unroll
      for (int ks = 0; ks < 2; ++ks)
        bfr[ni][ks] = *(const short8*)&Bb[(brow + ni * 16 + r) * 64 +
                                          ((ks * 32 + g * 8) ^ cswz)];
#pragma unroll
    for (int m = 0; m < 4; ++m)
#pragma unroll
      for (int ks = 0; ks < 2; ++ks)
        afr[m][ks] = *(const short8*)&Ab[(m * 16 + r) * 64 +
                                         ((ks * 32 + g * 8) ^ cswz)];
    if (t + 1 < NT) stage_half(A, bm + 128, K, koff + (t + 1) * 64,
                               &As[(t + 1) & 1][1][0][0], tid);
    __builtin_amdgcn_s_barrier();
    mfma_quad<0, 0>(acc, afr, bfr);
    __builtin_amdgcn_s_barrier();

    // -------- phase 2: read bfr[2..3] (4 reads)
#pragma unroll
    for (int ni = 2; ni < 4; ++ni)
#pragma unroll
      for (int ks = 0; ks < 2; ++ks)
        bfr[ni][ks] = *(const short8*)&Bb[(brow + ni * 16 + r) * 64 +
                                          ((ks * 32 + g * 8) ^ cswz)];
    __builtin_amdgcn_s_barrier();
    mfma_quad<0, 2>(acc, afr, bfr);
    __builtin_amdgcn_s_barrier();

    // -------- phase 3: re-read afr = A rows 64..127 (8 reads); stage B0(t+2)
#pragma unroll
    for (int m = 0; m < 4; ++m)
#pragma unroll
      for (int ks = 0; ks < 2; ++ks)
        afr[m][ks] = *(const short8*)&Ab[((64 + m * 16) + r) * 64 +
                                         ((ks * 32 + g * 8) ^ cswz)];
    if (t + 2 < NT) stage_half(B, bn, K, koff + (t + 2) * 64, &Bs[buf][0][0][0], tid);
    __builtin_amdgcn_s_barrier();
    mfma_quad<4, 2>(acc, afr, bfr);
    __builtin_amdgcn_s_barrier();

    // -------- phase 4: stage B1(t+2) + A0(t+2); counted vmcnt; last quad
    if (t + 2 < NT) {
      stage_half(B, bn + 128, K, koff + (t + 2) * 64, &Bs[buf][1][0][0], tid);
      stage_half(A, bm,       K, koff + (t + 2) * 64, &As[buf][0][0][0], tid);
    }
    if (t < NT - 2) asm volatile("s_waitcnt vmcnt(6)");  // tile t+1 landed
    else            asm volatile("s_waitcnt vmcnt(0)");  // epilogue drain
    __builtin_amdgcn_s_barrier();
    mfma_quad<4, 0>(acc, afr, bfr);
    __builtin_amdgcn_s_barrier();
  }

  // ---- epilogue: C/D layout col=lane&15, row=(lane>>4)*4+reg --------------
  float* Cfo = Cf + (size_t)ks_ * ((size_t)2048 * N);   // split-K partial slab
#pragma unroll
  for (int mi = 0; mi < 8; ++mi)
#pragma unroll
    for (int v = 0; v < 4; ++v) {
      int row = bm + wm * 128 + mi * 16 + g * 4 + v;
#pragma unroll
      for (int ni = 0; ni < 4; ++ni) {
        int col = bn + wn * 64 + ni * 16 + r;
        float x = acc[mi][ni][v];
        if (mode == 0) {
          x = fminf(8.0f, fmaxf(-8.0f, x));
          Cb[(size_t)row * N + col] = f2bf(x);
        } else {
          Cfo[(size_t)row * N + col] = x;
        }
      }
    }
}

// ---------------- fused RoPE + V-transpose (disjoint qkv columns) ----------------
// grid (14, 2048), block 256.
//   bx < 10 : RoPE on q (scaled) and k — h = bx*4 + tid/64 in [0,40), d = tid&63
//   bx >= 10: vtrans element idx = ((bx-10)*2048 + by)*256 + tid  (2^21 total)
__global__ void __launch_bounds__(256) ropevt_kernel(ushort* __restrict__ qkv,
                                                     const float* __restrict__ cosb,
                                                     const float* __restrict__ sinb,
                                                     ushort* __restrict__ vt) {
  int bx = blockIdx.x, t = blockIdx.y;
  if (bx < 10) {
    int h = bx * 4 + (threadIdx.x >> 6);
    int d = threadIdx.x & 63;
    size_t base = (size_t)t * QKV_N + (h < NH ? h * HD : KOFF + (h - NH) * HD);
    float x1 = bf2f(qkv[base + d]);
    float x2 = bf2f(qkv[base + 64 + d]);
    float c = cosb[t * 64 + d], s = sinb[t * 64 + d];
    float y1 = x1 * c - x2 * s;
    float y2 = x2 * c + x1 * s;
    if (h < NH) { y1 *= SCALE; y2 *= SCALE; }
    qkv[base + d]      = f2bf(y1);
    qkv[base + 64 + d] = f2bf(y2);
  } else {
    int idx = ((bx - 10) * 2048 + t) * 256 + threadIdx.x;  // kv(3b)|d(7b)|t(11b)
    int tt = idx & (T_TOK - 1);
    int d  = (idx >> 11) & (HD - 1);
    int kv = idx >> 18;
    vt[idx] = qkv[(size_t)tt * QKV_N + VOFF + kv * HD + d];
  }
}

// ---------------- flash attention: block = (q-tile 64, head), 4 waves x 16 rows --
// Staged (coalesced cooperative loads — R7 proved direct per-lane global reads
// are a latency disaster: 12KB/4KB lane strides, MfmaUtil 2%). T14 prefetch:
// next tile's K/V global loads issued right after the LDS writes. T5 setprio
// around MFMA clusters (+4-7% measured, m191). No Ps barrier (wave-private).
__global__ void __launch_bounds__(256) attn_kernel(const ushort* __restrict__ qkv,
                                                   const ushort* __restrict__ vt,
                                                   ushort* __restrict__ o) {
  __shared__ ushort Ks[64][136];    // +8 pad keeps 16B row alignment
  __shared__ ushort Vts[128][72];
  __shared__ ushort Ps[4][16][72];  // per-wave P round-trip (C->A layout)

  const int tid = threadIdx.x, wave = tid >> 6, lane = tid & 63;
  const int r = lane & 15, g = lane >> 4;
  const int qtile = blockIdx.x, head = blockIdx.y, kvh = head >> 2;
  const int q0 = qtile * 64;
  int s0;                                            // segment start (hardcoded cu)
  if (q0 < 512) s0 = 0; else if (q0 < 1280) s0 = 512;
  else if (q0 < 1664) s0 = 1280; else s0 = 1664;

  // Q fragments straight from global (A-layout: m=lane&15, k=(lane>>4)*8+j)
  short8 qf[4];
  const int qrow = q0 + wave * 16 + r;
#pragma unroll
  for (int ks = 0; ks < 4; ks++)
    qf[ks] = *(const short8*)&qkv[(size_t)qrow * QKV_N + head * HD + ks * 32 + g * 8];

  floatx4 zero = {0.f, 0.f, 0.f, 0.f};
  floatx4 oacc[8];
#pragma unroll
  for (int b = 0; b < 8; b++) oacc[b] = zero;
  float mrun[4] = {-1e30f, -1e30f, -1e30f, -1e30f};
  float lrun[4] = {0.f, 0.f, 0.f, 0.f};

  const size_t kcol  = (size_t)KOFF + kvh * HD;
  const size_t vbase = (size_t)kvh * HD * T_TOK;

  // ---- preload first tile's K/V into registers (coalesced) ----
  short8 kreg[4], vreg[4];
#pragma unroll
  for (int p = 0; p < 4; p++) {
    int krow = p * 16 + (tid >> 4), kc = (tid & 15) * 8;
    kreg[p] = *(const short8*)&qkv[(size_t)(s0 + krow) * QKV_N + kcol + kc];
    int vd = p * 32 + (tid >> 3), vc = (tid & 7) * 8;
    vreg[p] = *(const short8*)&vt[vbase + (size_t)vd * T_TOK + s0 + vc];
  }

  for (int k0 = s0; k0 < q0 + 64; k0 += 64) {
    __syncthreads();   // previous iter's LDS readers done
#pragma unroll
    for (int p = 0; p < 4; p++) {
      int krow = p * 16 + (tid >> 4), kc = (tid & 15) * 8;
      *(short8*)&Ks[krow][kc] = kreg[p];
      int vd = p * 32 + (tid >> 3), vc = (tid & 7) * 8;
      *(short8*)&Vts[vd][vc] = vreg[p];
    }
    __syncthreads();

    // ---- prefetch next tile's K/V (latency hidden under compute) ----
    if (k0 < q0) {
      int kn = k0 + 64;
#pragma unroll
      for (int p = 0; p < 4; p++) {
        int krow = p * 16 + (tid >> 4), kc = (tid & 15) * 8;
        kreg[p] = *(const short8*)&qkv[(size_t)(kn + krow) * QKV_N + kcol + kc];
        int vd = p * 32 + (tid >> 3), vc = (tid & 7) * 8;
        vreg[p] = *(const short8*)&vt[vbase + (size_t)vd * T_TOK + kn + vc];
      }
    }

    // ---- S = Q K^T (scale folded into Q) ----
    floatx4 sacc[4];
#pragma unroll
    for (int s = 0; s < 4; s++) sacc[s] = zero;
    __builtin_amdgcn_s_setprio(1);
#pragma unroll
    for (int s = 0; s < 4; s++)
#pragma unroll
      for (int ks = 0; ks < 4; ks++) {
        short8 kf = *(const short8*)&Ks[s * 16 + r][ks * 32 + g * 8];
        sacc[s] = __builtin_amdgcn_mfma_f32_16x16x32_bf16(qf[ks], kf, sacc[s], 0, 0, 0);
      }
    __builtin_amdgcn_s_setprio(0);

    // ---- causal mask (only diagonal tile needs it) ----
    const bool diag = (k0 == q0);
    float sv[4][4];
#pragma unroll
    for (int s = 0; s < 4; s++)
#pragma unroll
      for (int v = 0; v < 4; v++) {
        float x = sacc[s][v];
        if (diag) {
          int ka = k0 + s * 16 + r;            // key abs (col = lane&15)
          int qa = q0 + wave * 16 + g * 4 + v; // q   abs (row = (lane>>4)*4+reg)
          if (ka > qa) x = -1e30f;
        }
        sv[s][v] = x;
      }

    // ---- online softmax (rows live across lane&15 within each 16-lane group) --
    float rmax[4];
#pragma unroll
    for (int v = 0; v < 4; v++)
      rmax[v] = fmaxf(fmaxf(sv[0][v], sv[1][v]), fmaxf(sv[2][v], sv[3][v]));
#pragma unroll
    for (int off = 1; off < 16; off <<= 1)
#pragma unroll
      for (int v = 0; v < 4; v++)
        rmax[v] = fmaxf(rmax[v], __shfl_xor(rmax[v], off, 64));

    float newm[4], alpha[4];
#pragma unroll
    for (int v = 0; v < 4; v++) {
      newm[v]  = fmaxf(mrun[v], rmax[v]);
      alpha[v] = __expf(mrun[v] - newm[v]);
      mrun[v]  = newm[v];
    }

    float pv[4][4];
    float rsum[4] = {0.f, 0.f, 0.f, 0.f};
#pragma unroll
    for (int s = 0; s < 4; s++)
#pragma unroll
      for (int v = 0; v < 4; v++) {
        float p = __expf(sv[s][v] - newm[v]);
        pv[s][v] = p;
        rsum[v] += p;
      }
#pragma unroll
    for (int off = 1; off < 16; off <<= 1)
#pragma unroll
      for (int v = 0; v < 4; v++)
        rsum[v] += __shfl_xor(rsum[v], off, 64);
#pragma unroll
    for (int v = 0; v < 4; v++) lrun[v] = lrun[v] * alpha[v] + rsum[v];
#pragma unroll
    for (int b = 0; b < 8; b++)
#pragma unroll
      for (int v = 0; v < 4; v++) oacc[b][v] *= alpha[v];

    // ---- P: C-layout -> A-layout via per-wave LDS round trip (wave-private,
    //      in-wave lgkm ordering suffices, no barrier) ----
#pragma unroll
    for (int s = 0; s < 4; s++)
#pragma unroll
      for (int v = 0; v < 4; v++)
        Ps[wave][g * 4 + v][s * 16 + r] = f2bf(pv[s][v]);

    short8 pf0 = *(const short8*)&Ps[wave][r][g * 8];
    short8 pf1 = *(const short8*)&Ps[wave][r][32 + g * 8];

    // ---- O += P V  (B operand from V^T tile) ----
    __builtin_amdgcn_s_setprio(1);
#pragma unroll
    for (int b = 0; b < 8; b++) {
      short8 v0 = *(const short8*)&Vts[b * 16 + r][g * 8];
      short8 v1 = *(const short8*)&Vts[b * 16 + r][32 + g * 8];
      oacc[b] = __builtin_amdgcn_mfma_f32_16x16x32_bf16(pf0, v0, oacc[b], 0, 0, 0);
      oacc[b] = __builtin_amdgcn_mfma_f32_16x16x32_bf16(pf1, v1, oacc[b], 0, 0, 0);
    }
    __builtin_amdgcn_s_setprio(0);
  }

  // ---- epilogue: O /= l, write bf16 ----
  float rinv[4];
#pragma unroll
  for (int v = 0; v < 4; v++) rinv[v] = 1.0f / lrun[v];
#pragma unroll
  for (int b = 0; b < 8; b++)
#pragma unroll
    for (int v = 0; v < 4; v++) {
      int qa = q0 + wave * 16 + g * 4 + v;
      o[(size_t)qa * DM + head * HD + b * 16 + r] = f2bf(oacc[b][v] * rinv[v]);
    }
}

// ---------------- launch ----------------
extern "C" void kernel_launch(void* const* d_in, const int* in_sizes, int n_in,
                              void* d_out, int out_size, void* d_ws, size_t ws_size,
                              hipStream_t stream) {
  const float* hs   = (const float*)d_in[0];   // 2048 x 4096
  const float* wqkv = (const float*)d_in[1];   // 6144 x 4096
  const float* wo   = (const float*)d_in[2];   // 4096 x 4096
  const float* cosb = (const float*)d_in[3];   // 2048 x 64
  const float* sinb = (const float*)d_in[4];   // 2048 x 64
  float* out = (float*)d_out;                  // 2048 x 4096 fp32

  char* w = (char*)d_ws;
  ushort* h_bf   = (ushort*)(w);                  // 16,777,216 B
  ushort* wq_bf  = (ushort*)(w + 16777216);       // 50,331,648 B
  ushort* wo_bf  = (ushort*)(w + 67108864);       // 33,554,432 B
  ushort* qkv_bf = (ushort*)(w + 100663296);      // 25,165,824 B
  ushort* vt     = (ushort*)(w + 125829120);      //  4,194,304 B
  ushort* ao_bf  = (ushort*)(w + 130023424);      // 16,777,216 B  (total ~147 MB)
  // split-K partials reuse [w, w+67.1MB) — h_bf/wq_bf are dead after QKV GEMM
  float*  part   = (float*)(w);                   // 2 x 2048x4096 fp32 = 67,108,864 B

  // one fused cast: 12,582,912 float4 elements / 256 = 49,152 blocks
  cast3_kernel<<<49152, 256, 0, stream>>>(hs, wqkv, wo, h_bf, wq_bf, wo_bf);

  // QKV: M=2048, N=6144, K=4096 -> 24*8 = 192 blocks, no split
  gemm256<<<dim3(192), 512, 0, stream>>>(h_bf, wq_bf, qkv_bf, nullptr,
                                         QKV_N, DM, DM, 1, 0);
  // fused RoPE + V-transpose
  ropevt_kernel<<<dim3(14, T_TOK), 256, 0, stream>>>(qkv_bf, cosb, sinb, vt);
  attn_kernel<<<dim3(32, 32), 256, 0, stream>>>(qkv_bf, vt, ao_bf);
  // O-proj: M=2048, N=4096, K=4096, split-K=2 -> 16*8*2 = 256 blocks
  gemm256<<<dim3(256), 512, 0, stream>>>(ao_bf, wo_bf, nullptr, part,
                                         DM, DM, 2048, 2, 1);
  add_f32_kernel<<<8192, 256, 0, stream>>>((const float4*)part,
                                           (const float4*)(part + (size_t)2048 * 4096),
                                           (float4*)out, 2097152);
}

// Round 9
// 521.350 us; speedup vs baseline: 1.2750x; 1.0377x over previous
//
#include <hip/hip_runtime.h>

// ---------------- constants (reference is compile-time fixed) ----------------
#define T_TOK 2048
#define DM    4096
#define NH    32
#define KVH   8
#define HD    128
#define QKV_N 6144          // 4096 q + 1024 k + 1024 v
#define KOFF  4096
#define VOFF  5120
#define SCALE 0.08838834764831845f   // 128^-0.5

typedef __attribute__((ext_vector_type(8))) short  short8;   // 8 bf16 (4 VGPRs)
typedef __attribute__((ext_vector_type(4))) float  floatx4;  // MFMA acc

__device__ __forceinline__ ushort f2bf(float f) {
  union { float f; unsigned u; } x; x.f = f;
  unsigned u = x.u;
  return (ushort)((u + 0x7fffu + ((u >> 16) & 1u)) >> 16);   // RNE
}
__device__ __forceinline__ float bf2f(ushort h) {
  union { unsigned u; float f; } x; x.u = ((unsigned)h) << 16;
  return x.f;
}

// ---------------- fused fp32 -> bf16 cast of all three inputs ----------------
// ranges (in float4 units): hs 2,097,152 | wqkv 6,291,456 | wo 4,194,304.
// boundaries are multiples of 256 -> block-uniform branches. one launch.
__global__ void __launch_bounds__(256) cast3_kernel(const float* __restrict__ hs,
                                                    const float* __restrict__ wqkv,
                                                    const float* __restrict__ wo,
                                                    ushort* __restrict__ h_bf,
                                                    ushort* __restrict__ wq_bf,
                                                    ushort* __restrict__ wo_bf) {
  int i = blockIdx.x * 256 + threadIdx.x;
  const float* src; ushort* dst; int j;
  if (i < 2097152)        { src = hs;   dst = h_bf;  j = i; }
  else if (i < 8388608)   { src = wqkv; dst = wq_bf; j = i - 2097152; }
  else                    { src = wo;   dst = wo_bf; j = i - 8388608; }
  float4 v = ((const float4*)src)[j];
  ushort4 o;
  o.x = f2bf(v.x); o.y = f2bf(v.y); o.z = f2bf(v.z); o.w = f2bf(v.w);
  ((ushort4*)dst)[j] = o;
}

// ---------------- fp32 partial add (split-K reduction) ----------------
__global__ void __launch_bounds__(256) add_f32_kernel(const float4* __restrict__ a,
                                                      const float4* __restrict__ b,
                                                      float4* __restrict__ o, int n4) {
  int i = blockIdx.x * 256 + threadIdx.x;
  if (i >= n4) return;
  float4 x = a[i], y = b[i];
  o[i] = make_float4(x.x + y.x, x.y + y.y, x.z + y.z, x.w + y.w);
}

// ---------------- async global->LDS, 16B per lane ----------------
__device__ __forceinline__ void gld_lds16(const ushort* g, ushort* l) {
  __builtin_amdgcn_global_load_lds((const __attribute__((address_space(1))) unsigned int*)g,
                                   (__attribute__((address_space(3))) unsigned int*)l,
                                   16, 0, 0);
}

// ============================================================================
// 256x256 8-phase GEMM — EXACT round-2 structure (best measured: ~142-152 µs
// QKV, MfmaUtil 29, conflicts 0) + split-K plumbing (passed). Same-phase
// read+consume; staging ph1: A1(t+1), ph3: B0(t+2), ph4: B1+A0(t+2);
// vmcnt(6) once per tile at ph4 (never 0 in steady state); bare s_barrier.
// ============================================================================
template <int MLO, int NLO>
__device__ __forceinline__ void mfma_quad(floatx4 (&acc)[8][4],
                                          const short8 (&afr)[4][2],
                                          const short8 (&bfr)[4][2]) {
  __builtin_amdgcn_s_setprio(1);
#pragma unroll
  for (int ks = 0; ks < 2; ++ks)
#pragma unroll
    for (int mi = 0; mi < 4; ++mi)
#pragma unroll
      for (int ni = 0; ni < 2; ++ni)
        acc[MLO + mi][NLO + ni] = __builtin_amdgcn_mfma_f32_16x16x32_bf16(
            afr[mi][ks], bfr[NLO + ni][ks], acc[MLO + mi][NLO + ni], 0, 0, 0);
  __builtin_amdgcn_s_setprio(0);
}

// stage one 128x64 half-tile (16 KiB): 2 x global_load_lds per thread.
// linear LDS dest; source column chunk pre-swizzled by (row&7)  (rule 21).
__device__ __forceinline__ void stage_half(const ushort* __restrict__ G, size_t row0,
                                           int K, int k0, ushort* lbase, int tid) {
#pragma unroll
  for (int j = 0; j < 2; ++j) {
    int row   = j * 64 + (tid >> 3);
    int chunk = (tid & 7) ^ (row & 7);
    gld_lds16(G + (row0 + (size_t)row) * K + k0 + chunk * 8,
              lbase + (size_t)(j * 512 + tid) * 8);
  }
}

__global__ void __launch_bounds__(512, 2)
gemm256(const ushort* __restrict__ A, const ushort* __restrict__ B,
        ushort* __restrict__ Cb, float* __restrict__ Cf,
        int N, int K, int Kloc, int KS, int mode) {
  __shared__ __align__(16) ushort As[2][2][128][64];   // 64 KiB
  __shared__ __align__(16) ushort Bs[2][2][128][64];   // 64 KiB

  const int tid = threadIdx.x;
  const int lane = tid & 63, wv = tid >> 6;
  const int r = lane & 15, g = lane >> 4;
  const int wm = wv >> 2, wn = wv & 3;              // 2M x 4N wave grid

  // XCD-aware swizzle (nwg % 8 == 0 for all launches: 192, 256)
  const int nwg = (int)gridDim.x;
  const int wg  = (int)blockIdx.x;
  const int wgs = (wg & 7) * (nwg >> 3) + (wg >> 3);
  const int nbx = N >> 8;
  const int by  = wgs / (nbx * KS);
  const int rem = wgs - by * nbx * KS;
  const int bx  = rem / KS;
  const int ks_ = rem - bx * KS;                    // K-slice id
  const int bm = by * 256, bn = bx * 256;
  const int koff = ks_ * Kloc;

  const int NT = Kloc >> 6;                         // 64-wide K tiles

  floatx4 acc[8][4];
#pragma unroll
  for (int mi = 0; mi < 8; ++mi)
#pragma unroll
    for (int ni = 0; ni < 4; ++ni) acc[mi][ni] = (floatx4){0.f, 0.f, 0.f, 0.f};

  // ---- prologue: tile0 (B0,B1,A0,A1) + tile1 (B0,B1,A0) = 7 half-tiles ----
  stage_half(B, bn,       K, koff, &Bs[0][0][0][0], tid);
  stage_half(B, bn + 128, K, koff, &Bs[0][1][0][0], tid);
  stage_half(A, bm,       K, koff, &As[0][0][0][0], tid);
  stage_half(A, bm + 128, K, koff, &As[0][1][0][0], tid);
  if (NT > 1) {
    stage_half(B, bn,       K, koff + 64, &Bs[1][0][0][0], tid);
    stage_half(B, bn + 128, K, koff + 64, &Bs[1][1][0][0], tid);
    stage_half(A, bm,       K, koff + 64, &As[1][0][0][0], tid);
    asm volatile("s_waitcnt vmcnt(6)");   // tile0's 8 loads landed
  } else {
    asm volatile("s_waitcnt vmcnt(0)");
  }
  __builtin_amdgcn_s_barrier();

  short8 afr[4][2], bfr[4][2];
  const int cswz = (r & 7) << 3;        // element-index XOR for 16B-chunk swz

  for (int t = 0; t < NT; ++t) {
    const int buf = t & 1;
    const ushort* Ab = &As[buf][wm][0][0];
    const ushort* Bb = &Bs[buf][wn >> 1][0][0];
    const int brow = (wn & 1) * 64;

    // -------- phase 1: read bfr[0..1] + afr[0..3] (12 reads); stage A1(t+1)
#pragma unroll
    for (int ni = 0; ni < 2; ++ni)
#pragma unroll
      for (int ks = 0; ks < 2; ++ks)
        bfr[ni][ks] = *(const short8*)&Bb[(brow + ni * 16 + r) * 64 +
                                          ((ks * 32 + g * 8) ^ cswz)];
#pragma unroll
    for (int m = 0; m < 4; ++m)
#pragma unroll
      for (int ks = 0; ks < 2; ++ks)
        afr[m][ks] = *(const short8*)&Ab[(m * 16 + r) * 64 +
                                         ((ks * 32 + g * 8) ^ cswz)];
    if (t + 1 < NT) stage_half(A, bm + 128, K, koff + (t + 1) * 64,
                               &As[(t + 1) & 1][1][0][0], tid);
    __builtin_amdgcn_s_barrier();
    mfma_quad<0, 0>(acc, afr, bfr);
    __builtin_amdgcn_s_barrier();

    // -------- phase 2: read bfr[2..3] (4 reads)
#pragma unroll
    for (int ni = 2; ni < 4; ++ni)
#pragma unroll
      for (int ks = 0; ks < 2; ++ks)
        bfr[ni][ks] = *(const short8*)&Bb[(brow + ni * 16 + r) * 64 +
                                          ((ks * 32 + g * 8) ^ cswz)];
    __builtin_amdgcn_s_barrier();
    mfma_quad<0, 2>(acc, afr, bfr);
    __builtin_amdgcn_s_barrier();

    // -------- phase 3: re-read afr = A rows 64..127 (8 reads); stage B0(t+2)
#pragma unroll
    for (int m = 0; m < 4; ++m)
#pragma unroll
      for (int ks = 0; ks < 2; ++ks)
        afr[m][ks] = *(const short8*)&Ab[((64 + m * 16) + r) * 64 +
                                         ((ks * 32 + g * 8) ^ cswz)];
    if (t + 2 < NT) stage_half(B, bn, K, koff + (t + 2) * 64, &Bs[buf][0][0][0], tid);
    __builtin_amdgcn_s_barrier();
    mfma_quad<4, 2>(acc, afr, bfr);
    __builtin_amdgcn_s_barrier();

    // -------- phase 4: stage B1(t+2) + A0(t+2); counted vmcnt; last quad
    if (t + 2 < NT) {
      stage_half(B, bn + 128, K, koff + (t + 2) * 64, &Bs[buf][1][0][0], tid);
      stage_half(A, bm,       K, koff + (t + 2) * 64, &As[buf][0][0][0], tid);
    }
    if (t < NT - 2) asm volatile("s_waitcnt vmcnt(6)");  // tile t+1 landed
    else            asm volatile("s_waitcnt vmcnt(0)");  // epilogue drain
    __builtin_amdgcn_s_barrier();
    mfma_quad<4, 0>(acc, afr, bfr);
    __builtin_amdgcn_s_barrier();
  }

  // ---- epilogue: C/D layout col=lane&15, row=(lane>>4)*4+reg --------------
  float* Cfo = Cf + (size_t)ks_ * ((size_t)2048 * N);   // split-K partial slab
#pragma unroll
  for (int mi = 0; mi < 8; ++mi)
#pragma unroll
    for (int v = 0; v < 4; ++v) {
      int row = bm + wm * 128 + mi * 16 + g * 4 + v;
#pragma unroll
      for (int ni = 0; ni < 4; ++ni) {
        int col = bn + wn * 64 + ni * 16 + r;
        float x = acc[mi][ni][v];
        if (mode == 0) {
          x = fminf(8.0f, fmaxf(-8.0f, x));
          Cb[(size_t)row * N + col] = f2bf(x);
        } else {
          Cfo[(size_t)row * N + col] = x;
        }
      }
    }
}

// ---------------- fused RoPE + V-transpose (disjoint qkv columns) ----------------
// grid (14, 2048), block 256.
//   bx < 10 : RoPE on q (scaled) and k — h = bx*4 + tid/64 in [0,40), d = tid&63
//   bx >= 10: vtrans element idx = ((bx-10)*2048 + by)*256 + tid  (2^21 total)
__global__ void __launch_bounds__(256) ropevt_kernel(ushort* __restrict__ qkv,
                                                     const float* __restrict__ cosb,
                                                     const float* __restrict__ sinb,
                                                     ushort* __restrict__ vt) {
  int bx = blockIdx.x, t = blockIdx.y;
  if (bx < 10) {
    int h = bx * 4 + (threadIdx.x >> 6);
    int d = threadIdx.x & 63;
    size_t base = (size_t)t * QKV_N + (h < NH ? h * HD : KOFF + (h - NH) * HD);
    float x1 = bf2f(qkv[base + d]);
    float x2 = bf2f(qkv[base + 64 + d]);
    float c = cosb[t * 64 + d], s = sinb[t * 64 + d];
    float y1 = x1 * c - x2 * s;
    float y2 = x2 * c + x1 * s;
    if (h < NH) { y1 *= SCALE; y2 *= SCALE; }
    qkv[base + d]      = f2bf(y1);
    qkv[base + 64 + d] = f2bf(y2);
  } else {
    int idx = ((bx - 10) * 2048 + t) * 256 + threadIdx.x;  // kv(3b)|d(7b)|t(11b)
    int tt = idx & (T_TOK - 1);
    int d  = (idx >> 11) & (HD - 1);
    int kv = idx >> 18;
    vt[idx] = qkv[(size_t)tt * QKV_N + VOFF + kv * HD + d];
  }
}

// ---------------- flash attention: q-tile 128, 8 waves x 16 rows, 512 thr ----
// R8 ledger: attn ~130-150 µs, latency/sync-bound (R7: MfmaUtil ~2%). Fix:
// amortize K/V staging + barriers over 2x the Q-rows per block (q-tile 64->128,
// 4->8 waves). Same per-wave math; staging traffic per block unchanged but
// serves double the output. LDS 54 KB -> 2 blocks/CU -> 16 waves/CU TLP.
// Causal mask now applied ELEMENTWISE on every tile (ka>qa -> -inf): zero
// correctness risk; fully-masked tiles for low waves produce P=0 (harmless,
// MFMA is ~2% utilized). Segment starts 512/1280/1664 all multiples of 128.
__global__ void __launch_bounds__(512) attn_kernel(const ushort* __restrict__ qkv,
                                                   const ushort* __restrict__ vt,
                                                   ushort* __restrict__ o) {
  __shared__ ushort Ks[64][136];    // +8 pad keeps 16B row alignment
  __shared__ ushort Vts[128][72];
  __shared__ ushort Ps[8][16][72];  // per-wave P round-trip (C->A layout)

  const int tid = threadIdx.x, wave = tid >> 6, lane = tid & 63;
  const int r = lane & 15, g = lane >> 4;
  const int qtile = blockIdx.x, head = blockIdx.y, kvh = head >> 2;
  const int q0 = qtile * 128;
  int s0;                                            // segment start (hardcoded cu)
  if (q0 < 512) s0 = 0; else if (q0 < 1280) s0 = 512;
  else if (q0 < 1664) s0 = 1280; else s0 = 1664;

  // Q fragments straight from global (A-layout: m=lane&15, k=(lane>>4)*8+j)
  short8 qf[4];
  const int qrow = q0 + wave * 16 + r;
#pragma unroll
  for (int ks = 0; ks < 4; ks++)
    qf[ks] = *(const short8*)&qkv[(size_t)qrow * QKV_N + head * HD + ks * 32 + g * 8];

  floatx4 zero = {0.f, 0.f, 0.f, 0.f};
  floatx4 oacc[8];
#pragma unroll
  for (int b = 0; b < 8; b++) oacc[b] = zero;
  float mrun[4] = {-1e30f, -1e30f, -1e30f, -1e30f};
  float lrun[4] = {0.f, 0.f, 0.f, 0.f};

  const size_t kcol  = (size_t)KOFF + kvh * HD;
  const size_t vbase = (size_t)kvh * HD * T_TOK;

  // ---- preload first tile's K/V into registers (coalesced, 512 thr) ----
  // K tile: 64 rows x 16 chunks = 1024 slots; V^T tile: 128 d x 8 chunks.
  short8 kreg[2], vreg[2];
#pragma unroll
  for (int p = 0; p < 2; p++) {
    int slot = p * 512 + tid;
    int krow = slot >> 4, kc = (slot & 15) * 8;
    kreg[p] = *(const short8*)&qkv[(size_t)(s0 + krow) * QKV_N + kcol + kc];
    int vd = slot >> 3, vc = (slot & 7) * 8;
    vreg[p] = *(const short8*)&vt[vbase + (size_t)vd * T_TOK + s0 + vc];
  }

  for (int k0 = s0; k0 < q0 + 128; k0 += 64) {
    __syncthreads();   // previous iter's LDS readers done
#pragma unroll
    for (int p = 0; p < 2; p++) {
      int slot = p * 512 + tid;
      int krow = slot >> 4, kc = (slot & 15) * 8;
      *(short8*)&Ks[krow][kc] = kreg[p];
      int vd = slot >> 3, vc = (slot & 7) * 8;
      *(short8*)&Vts[vd][vc] = vreg[p];
    }
    __syncthreads();

    // ---- prefetch next tile's K/V (latency hidden under compute) ----
    if (k0 < q0 + 64) {
      int kn = k0 + 64;
#pragma unroll
      for (int p = 0; p < 2; p++) {
        int slot = p * 512 + tid;
        int krow = slot >> 4, kc = (slot & 15) * 8;
        kreg[p] = *(const short8*)&qkv[(size_t)(kn + krow) * QKV_N + kcol + kc];
        int vd = slot >> 3, vc = (slot & 7) * 8;
        vreg[p] = *(const short8*)&vt[vbase + (size_t)vd * T_TOK + kn + vc];
      }
    }

    // ---- S = Q K^T (scale folded into Q) ----
    floatx4 sacc[4];
#pragma unroll
    for (int s = 0; s < 4; s++) sacc[s] = zero;
    __builtin_amdgcn_s_setprio(1);
#pragma unroll
    for (int s = 0; s < 4; s++)
#pragma unroll
      for (int ks = 0; ks < 4; ks++) {
        short8 kf = *(const short8*)&Ks[s * 16 + r][ks * 32 + g * 8];
        sacc[s] = __builtin_amdgcn_mfma_f32_16x16x32_bf16(qf[ks], kf, sacc[s], 0, 0, 0);
      }
    __builtin_amdgcn_s_setprio(0);

    // ---- causal mask: elementwise on every tile (cheap; zero-risk) ----
    float sv[4][4];
#pragma unroll
    for (int s = 0; s < 4; s++)
#pragma unroll
      for (int v = 0; v < 4; v++) {
        float x = sacc[s][v];
        int ka = k0 + s * 16 + r;            // key abs (col = lane&15)
        int qa = q0 + wave * 16 + g * 4 + v; // q   abs (row = (lane>>4)*4+reg)
        if (ka > qa) x = -1e30f;
        sv[s][v] = x;
      }

    // ---- online softmax (rows live across lane&15 within each 16-lane group) --
    float rmax[4];
#pragma unroll
    for (int v = 0; v < 4; v++)
      rmax[v] = fmaxf(fmaxf(sv[0][v], sv[1][v]), fmaxf(sv[2][v], sv[3][v]));
#pragma unroll
    for (int off = 1; off < 16; off <<= 1)
#pragma unroll
      for (int v = 0; v < 4; v++)
        rmax[v] = fmaxf(rmax[v], __shfl_xor(rmax[v], off, 64));

    float newm[4], alpha[4];
#pragma unroll
    for (int v = 0; v < 4; v++) {
      newm[v]  = fmaxf(mrun[v], rmax[v]);
      alpha[v] = __expf(mrun[v] - newm[v]);
      mrun[v]  = newm[v];
    }

    float pv[4][4];
    float rsum[4] = {0.f, 0.f, 0.f, 0.f};
#pragma unroll
    for (int s = 0; s < 4; s++)
#pragma unroll
      for (int v = 0; v < 4; v++) {
        float p = __expf(sv[s][v] - newm[v]);
        pv[s][v] = p;
        rsum[v] += p;
      }
#pragma unroll
    for (int off = 1; off < 16; off <<= 1)
#pragma unroll
      for (int v = 0; v < 4; v++)
        rsum[v] += __shfl_xor(rsum[v], off, 64);
#pragma unroll
    for (int v = 0; v < 4; v++) lrun[v] = lrun[v] * alpha[v] + rsum[v];
#pragma unroll
    for (int b = 0; b < 8; b++)
#pragma unroll
      for (int v = 0; v < 4; v++) oacc[b][v] *= alpha[v];

    // ---- P: C-layout -> A-layout via per-wave LDS round trip (wave-private,
    //      in-wave lgkm ordering suffices, no barrier) ----
#pragma unroll
    for (int s = 0; s < 4; s++)
#pragma unroll
      for (int v = 0; v < 4; v++)
        Ps[wave][g * 4 + v][s * 16 + r] = f2bf(pv[s][v]);

    short8 pf0 = *(const short8*)&Ps[wave][r][g * 8];
    short8 pf1 = *(const short8*)&Ps[wave][r][32 + g * 8];

    // ---- O += P V  (B operand from V^T tile) ----
    __builtin_amdgcn_s_setprio(1);
#pragma unroll
    for (int b = 0; b < 8; b++) {
      short8 v0 = *(const short8*)&Vts[b * 16 + r][g * 8];
      short8 v1 = *(const short8*)&Vts[b * 16 + r][32 + g * 8];
      oacc[b] = __builtin_amdgcn_mfma_f32_16x16x32_bf16(pf0, v0, oacc[b], 0, 0, 0);
      oacc[b] = __builtin_amdgcn_mfma_f32_16x16x32_bf16(pf1, v1, oacc[b], 0, 0, 0);
    }
    __builtin_amdgcn_s_setprio(0);
  }

  // ---- epilogue: O /= l, write bf16 ----
  float rinv[4];
#pragma unroll
  for (int v = 0; v < 4; v++) rinv[v] = 1.0f / lrun[v];
#pragma unroll
  for (int b = 0; b < 8; b++)
#pragma unroll
    for (int v = 0; v < 4; v++) {
      int qa = q0 + wave * 16 + g * 4 + v;
      o[(size_t)qa * DM + head * HD + b * 16 + r] = f2bf(oacc[b][v] * rinv[v]);
    }
}

// ---------------- launch ----------------
extern "C" void kernel_launch(void* const* d_in, const int* in_sizes, int n_in,
                              void* d_out, int out_size, void* d_ws, size_t ws_size,
                              hipStream_t stream) {
  const float* hs   = (const float*)d_in[0];   // 2048 x 4096
  const float* wqkv = (const float*)d_in[1];   // 6144 x 4096
  const float* wo   = (const float*)d_in[2];   // 4096 x 4096
  const float* cosb = (const float*)d_in[3];   // 2048 x 64
  const float* sinb = (const float*)d_in[4];   // 2048 x 64
  float* out = (float*)d_out;                  // 2048 x 4096 fp32

  char* w = (char*)d_ws;
  ushort* h_bf   = (ushort*)(w);                  // 16,777,216 B
  ushort* wq_bf  = (ushort*)(w + 16777216);       // 50,331,648 B
  ushort* wo_bf  = (ushort*)(w + 67108864);       // 33,554,432 B
  ushort* qkv_bf = (ushort*)(w + 100663296);      // 25,165,824 B
  ushort* vt     = (ushort*)(w + 125829120);      //  4,194,304 B
  ushort* ao_bf  = (ushort*)(w + 130023424);      // 16,777,216 B  (total ~147 MB)
  // split-K partials reuse [w, w+67.1MB) — h_bf/wq_bf are dead after QKV GEMM
  float*  part   = (float*)(w);                   // 2 x 2048x4096 fp32 = 67,108,864 B

  // one fused cast: 12,582,912 float4 elements / 256 = 49,152 blocks
  cast3_kernel<<<49152, 256, 0, stream>>>(hs, wqkv, wo, h_bf, wq_bf, wo_bf);

  // QKV: M=2048, N=6144, K=4096 -> 24*8 = 192 blocks, no split
  gemm256<<<dim3(192), 512, 0, stream>>>(h_bf, wq_bf, qkv_bf, nullptr,
                                         QKV_N, DM, DM, 1, 0);
  // fused RoPE + V-transpose
  ropevt_kernel<<<dim3(14, T_TOK), 256, 0, stream>>>(qkv_bf, cosb, sinb, vt);
  // attn: q-tile 128, 8 waves -> 16 x 32 = 512 blocks
  attn_kernel<<<dim3(16, 32), 512, 0, stream>>>(qkv_bf, vt, ao_bf);
  // O-proj: M=2048, N=4096, K=4096, split-K=2 -> 16*8*2 = 256 blocks
  gemm256<<<dim3(256), 512, 0, stream>>>(ao_bf, wo_bf, nullptr, part,
                                         DM, DM, 2048, 2, 1);
  add_f32_kernel<<<8192, 256, 0, stream>>>((const float4*)part,
                                           (const float4*)(part + (size_t)2048 * 4096),
                                           (float4*)out, 2097152);
}